// Round 4
// baseline (422.385 us; speedup 1.0000x reference)
//
#include <hip/hip_runtime.h>
#include <hip/hip_bf16.h>
#include <math.h>

// GCN 2-layer: out = log_softmax( GCN2( relu( GCN1(x) ) ) )
// GCNConv: out = D^-1/2 A D^-1/2 (X W) + (X W)/deg + b,  deg = 1 + indeg(dst)
//
// Round 4: (1) non-temporal edge-list loads in build_csr so the 8x dst rescan
// stops evicting the dirty scatter lines from the XCD-local L2 (round-3 showed
// WRITE_SIZE stuck at 78MB = ~8x mid-fill evictions); grid 2048 for full
// occupancy. (2) hw2 padded to 128B-aligned rows (was 96B straddling lines).
// (3) unroll-8 gathers, tail-free via zero-weight slots.

#define CAP 64
typedef unsigned short u16;

__device__ __forceinline__ u16 f2bf(float f) {
    __hip_bfloat16 h = __float2bfloat16(f);
    return *reinterpret_cast<u16*>(&h);
}
__device__ __forceinline__ float bf2f(u16 u) {
    return __uint_as_float(((unsigned)u) << 16);
}

// ---------------- CSR build, dst-range partitioned (8 groups ~ 8 XCDs) ----------------
// Group g = blockIdx%8 owns nodes [g*chunk, (g+1)*chunk). Scatter writes stay in
// a 3.2MB slice resident in one XCD's L2; edge streams are non-temporal so they
// don't evict the dirty slice.

__global__ __launch_bounds__(256) void build_csr(const int* __restrict__ src,
                                                 const int* __restrict__ dst,
                                                 int* __restrict__ cnt,
                                                 int* __restrict__ csr_src,
                                                 int E, int chunk) {
    const int g = blockIdx.x & 7;
    const int slice = blockIdx.x >> 3;
    const int nsl = gridDim.x >> 3;
    const int lo = g * chunk, hi = lo + chunk;
    for (int e = slice * 256 + threadIdx.x; e < E; e += nsl * 256) {
        int d = __builtin_nontemporal_load(&dst[e]);
        if (d >= lo && d < hi) {
            int s = __builtin_nontemporal_load(&src[e]);
            int slot = atomicAdd(&cnt[d], 1);
            if (slot < CAP) csr_src[d * CAP + slot] = s;
        }
    }
}

__global__ __launch_bounds__(256) void compute_dinv(const int* __restrict__ cnt,
                                                    float* __restrict__ dinv, int N) {
    int v = blockIdx.x * 256 + threadIdx.x;
    if (v < N) dinv[v] = rsqrtf((float)cnt[v] + 1.0f);
}

// ---------------- tiled fp32 GEMM -> bf16 out: OUT[N,OSTR] = X[N,K] @ W[K,OUTC] ----------------

template <int K, int OUTC, int OSTR>
__global__ __launch_bounds__(256) void gemm_tiled(const float* __restrict__ X,
                                                  const float* __restrict__ W,
                                                  u16* __restrict__ OUT, int N) {
    constexpr int KP = K + 4;
    __shared__ float xs[64 * KP];
    __shared__ float Wp[K * 64];
    const int t = threadIdx.x;
    const int row0 = blockIdx.x * 64;

    for (int i = t; i < K * 64; i += 256) {
        int k = i >> 6, c = i & 63;
        Wp[i] = (c < OUTC) ? W[k * OUTC + c] : 0.f;
    }
    constexpr int KQ = K / 4;
    const float4* X4 = reinterpret_cast<const float4*>(X);
    for (int i = t; i < 64 * KQ; i += 256) {
        int r = i / KQ, kq = i - r * KQ;
        int m = row0 + r;
        float4 v = make_float4(0.f, 0.f, 0.f, 0.f);
        if (m < N) v = X4[(size_t)m * KQ + kq];
        *reinterpret_cast<float4*>(&xs[r * KP + kq * 4]) = v;
    }
    __syncthreads();

    const int c4 = (t & 15) * 4;
    const int r4 = (t >> 4) * 4;
    float acc[4][4] = {};
    for (int k = 0; k < K; k += 4) {
        float4 A[4], B[4];
        #pragma unroll
        for (int i = 0; i < 4; i++)
            A[i] = *reinterpret_cast<const float4*>(&xs[(r4 + i) * KP + k]);
        #pragma unroll
        for (int kk = 0; kk < 4; kk++)
            B[kk] = *reinterpret_cast<const float4*>(&Wp[(k + kk) * 64 + c4]);
        const float* Af = reinterpret_cast<const float*>(A);
        const float* Bf = reinterpret_cast<const float*>(B);
        #pragma unroll
        for (int i = 0; i < 4; i++)
            #pragma unroll
            for (int kk = 0; kk < 4; kk++) {
                float av = Af[i * 4 + kk];
                #pragma unroll
                for (int j = 0; j < 4; j++)
                    acc[i][j] = fmaf(av, Bf[kk * 4 + j], acc[i][j]);
            }
    }
    #pragma unroll
    for (int i = 0; i < 4; i++) {
        int m = row0 + r4 + i;
        if (m >= N) continue;
        ushort4 o;
        o.x = f2bf(acc[i][0]); o.y = f2bf(acc[i][1]);
        o.z = f2bf(acc[i][2]); o.w = f2bf(acc[i][3]);
        *reinterpret_cast<ushort4*>(&OUT[(size_t)m * OSTR + c4]) = o;
    }
}

// ---------------- layer-1 aggregation: h = relu(agg + xw/deg + b1), F=64 ----------------
// one wave per node, lane = feature; lanes >= c carry sl=0/wl=0 so the unroll-8
// loop runs tail-free to (c+7)&~7 (extra gathers hit the hot row 0 with weight 0).

__global__ __launch_bounds__(256) void agg1_relu(const u16* __restrict__ xw,
                                                 const int* __restrict__ csr_src,
                                                 const int* __restrict__ cnt,
                                                 const float* __restrict__ dinv,
                                                 const float* __restrict__ bias,
                                                 float* __restrict__ h, int N) {
    int v = (blockIdx.x * 256 + threadIdx.x) >> 6;
    int f = threadIdx.x & 63;
    if (v >= N) return;
    int c = cnt[v]; if (c > CAP) c = CAP;
    int base = v * CAP;
    float dv = dinv[v];
    int sl = 0; float wl = 0.f;
    if (f < c) { sl = csr_src[base + f]; wl = dinv[sl] * dv; }
    float acc = 0.f;
    int c8 = (c + 7) & ~7;
    for (int j = 0; j < c8; j += 8) {
        int s[8]; float w[8]; float xv[8];
        #pragma unroll
        for (int u = 0; u < 8; u++) {
            s[u] = __shfl(sl, j + u);
            w[u] = __shfl(wl, j + u);
        }
        #pragma unroll
        for (int u = 0; u < 8; u++)
            xv[u] = bf2f(xw[(size_t)s[u] * 64 + f]);
        #pragma unroll
        for (int u = 0; u < 8; u++)
            acc = fmaf(xv[u], w[u], acc);
    }
    acc = fmaf(bf2f(xw[(size_t)v * 64 + f]), dv * dv, acc);
    acc += bias[f];
    h[(size_t)v * 64 + f] = fmaxf(acc, 0.f);
}

// ---------------- layer-2 aggregation fused with log_softmax, F=47 (stride 64) ----------------

__global__ __launch_bounds__(256) void agg2_lsm(const u16* __restrict__ hw,
                                                const int* __restrict__ csr_src,
                                                const int* __restrict__ cnt,
                                                const float* __restrict__ dinv,
                                                const float* __restrict__ bias,
                                                float* __restrict__ out, int N) {
    int v = (blockIdx.x * 256 + threadIdx.x) >> 6;
    int f = threadIdx.x & 63;
    if (v >= N) return;
    int c = cnt[v]; if (c > CAP) c = CAP;
    int base = v * CAP;
    float dv = dinv[v];
    int sl = 0; float wl = 0.f;
    if (f < c) { sl = csr_src[base + f]; wl = dinv[sl] * dv; }
    const bool act = (f < 47);
    float acc = 0.f;
    int c8 = (c + 7) & ~7;
    for (int j = 0; j < c8; j += 8) {
        int s[8]; float w[8]; float xv[8];
        #pragma unroll
        for (int u = 0; u < 8; u++) {
            s[u] = __shfl(sl, j + u);
            w[u] = __shfl(wl, j + u);
        }
        #pragma unroll
        for (int u = 0; u < 8; u++)
            xv[u] = act ? bf2f(hw[(size_t)s[u] * 64 + f]) : 0.f;
        #pragma unroll
        for (int u = 0; u < 8; u++)
            acc = fmaf(xv[u], w[u], acc);
    }
    float val;
    if (act) {
        acc = fmaf(bf2f(hw[(size_t)v * 64 + f]), dv * dv, acc);
        acc += bias[f];
        val = acc;
    } else {
        val = -INFINITY;
    }
    float m = val;
    #pragma unroll
    for (int mask = 1; mask < 64; mask <<= 1)
        m = fmaxf(m, __shfl_xor(m, mask));
    float e = act ? __expf(val - m) : 0.f;
    float ssum = e;
    #pragma unroll
    for (int mask = 1; mask < 64; mask <<= 1)
        ssum += __shfl_xor(ssum, mask);
    if (act) out[(size_t)v * 47 + f] = val - m - __logf(ssum);
}

// ---------------- launch ----------------

extern "C" void kernel_launch(void* const* d_in, const int* in_sizes, int n_in,
                              void* d_out, int out_size, void* d_ws, size_t ws_size,
                              hipStream_t stream) {
    const float* x  = (const float*)d_in[0];
    const int*   ei = (const int*)d_in[1];
    const float* W1 = (const float*)d_in[2];
    const float* b1 = (const float*)d_in[3];
    const float* W2 = (const float*)d_in[4];
    const float* b2 = (const float*)d_in[5];
    float* out = (float*)d_out;

    const int N = in_sizes[0] / 128;
    const int E = in_sizes[1] / 2;
    const int* src = ei;
    const int* dst = ei + E;

    char* ws = (char*)d_ws;
    size_t off = 0;
    auto alloc = [&](size_t bytes) {
        void* p = ws + off;
        off += (bytes + 255) & ~(size_t)255;
        return p;
    };
    int*   cnt     = (int*)  alloc((size_t)N * 4);
    float* dinv    = (float*)alloc((size_t)N * 4);
    int*   csr_src = (int*)  alloc((size_t)N * CAP * 4);
    u16*   xw1     = (u16*)  alloc((size_t)N * 64 * 2);   // bf16 [N,64], 128B rows
    float* hbuf    = (float*)alloc((size_t)N * 64 * 4);   // fp32 [N,64]
    u16*   hw2     = (u16*)  alloc((size_t)N * 64 * 2);   // bf16 [N,64], 47 used, 128B rows

    const int chunk = (N + 7) / 8;

    hipMemsetAsync(cnt, 0, (size_t)N * 4, stream);
    build_csr<<<2048, 256, 0, stream>>>(src, dst, cnt, csr_src, E, chunk);
    compute_dinv<<<(N + 255) / 256, 256, 0, stream>>>(cnt, dinv, N);

    gemm_tiled<128, 64, 64><<<(N + 63) / 64, 256, 0, stream>>>(x, W1, xw1, N);
    agg1_relu<<<(N + 3) / 4, 256, 0, stream>>>(xw1, csr_src, cnt, dinv, b1, hbuf, N);
    gemm_tiled<64, 47, 64><<<(N + 63) / 64, 256, 0, stream>>>(hbuf, W2, hw2, N);
    agg2_lsm<<<(N + 3) / 4, 256, 0, stream>>>(hw2, csr_src, cnt, dinv, b2, out, N);
}

// Round 5
// 384.404 us; speedup vs baseline: 1.0988x; 1.0988x over previous
//
#include <hip/hip_runtime.h>
#include <hip/hip_bf16.h>
#include <math.h>

// GCN 2-layer: out = log_softmax( GCN2( relu( GCN1(x) ) ) )
// GCNConv: out = D^-1/2 A D^-1/2 (X W) + (X W)/deg + b,  deg = 1 + indeg(dst)
//
// Round 5: aggregation restructured for 8-rows-per-instruction gathers.
// Lane i = (edge r=i>>3, feature-block b=i&7); each lane loads uint4 (8 bf16,
// 16B) -> one wave vmem instruction fetches 8 full 128B rows. Fixes the
// latency-bound 1-line-per-instruction gather seen in round 4 (agg2: 122us,
// VALUBusy 30%, HBM 11.5%). Self-loop = virtual edge with weight dinv^2.
// build_csr reverted to round-3 form (non-temporal loads regressed it).

#define CAP 64
typedef unsigned short u16;

__device__ __forceinline__ u16 f2bf(float f) {
    __hip_bfloat16 h = __float2bfloat16(f);
    return *reinterpret_cast<u16*>(&h);
}

// ---------------- CSR build, dst-range partitioned (8 groups ~ 8 XCDs) ----------------
// Round-3 known-good: 85us. Scatter slice (3.2MB) ~L2-resident per XCD.

__global__ __launch_bounds__(256) void build_csr(const int* __restrict__ src,
                                                 const int* __restrict__ dst,
                                                 int* __restrict__ cnt,
                                                 int* __restrict__ csr_src,
                                                 int E, int chunk) {
    const int g = blockIdx.x & 7;
    const int slice = blockIdx.x >> 3;
    const int nsl = gridDim.x >> 3;
    const int lo = g * chunk, hi = lo + chunk;
    for (int e = slice * 256 + threadIdx.x; e < E; e += nsl * 256) {
        int d = dst[e];
        if (d >= lo && d < hi) {
            int slot = atomicAdd(&cnt[d], 1);
            if (slot < CAP) csr_src[d * CAP + slot] = src[e];
        }
    }
}

__global__ __launch_bounds__(256) void compute_dinv(const int* __restrict__ cnt,
                                                    float* __restrict__ dinv, int N) {
    int v = blockIdx.x * 256 + threadIdx.x;
    if (v < N) dinv[v] = rsqrtf((float)cnt[v] + 1.0f);
}

// ---------------- tiled fp32 GEMM -> bf16 out: OUT[N,OSTR] = X[N,K] @ W[K,OUTC] ----------------
// Writes ALL OSTR cols (cols >= OUTC are zeros) — required by the full-row gathers.

template <int K, int OUTC, int OSTR>
__global__ __launch_bounds__(256) void gemm_tiled(const float* __restrict__ X,
                                                  const float* __restrict__ W,
                                                  u16* __restrict__ OUT, int N) {
    constexpr int KP = K + 4;
    __shared__ float xs[64 * KP];
    __shared__ float Wp[K * 64];
    const int t = threadIdx.x;
    const int row0 = blockIdx.x * 64;

    for (int i = t; i < K * 64; i += 256) {
        int k = i >> 6, c = i & 63;
        Wp[i] = (c < OUTC) ? W[k * OUTC + c] : 0.f;
    }
    constexpr int KQ = K / 4;
    const float4* X4 = reinterpret_cast<const float4*>(X);
    for (int i = t; i < 64 * KQ; i += 256) {
        int r = i / KQ, kq = i - r * KQ;
        int m = row0 + r;
        float4 v = make_float4(0.f, 0.f, 0.f, 0.f);
        if (m < N) v = X4[(size_t)m * KQ + kq];
        *reinterpret_cast<float4*>(&xs[r * KP + kq * 4]) = v;
    }
    __syncthreads();

    const int c4 = (t & 15) * 4;
    const int r4 = (t >> 4) * 4;
    float acc[4][4] = {};
    for (int k = 0; k < K; k += 4) {
        float4 A[4], B[4];
        #pragma unroll
        for (int i = 0; i < 4; i++)
            A[i] = *reinterpret_cast<const float4*>(&xs[(r4 + i) * KP + k]);
        #pragma unroll
        for (int kk = 0; kk < 4; kk++)
            B[kk] = *reinterpret_cast<const float4*>(&Wp[(k + kk) * 64 + c4]);
        const float* Af = reinterpret_cast<const float*>(A);
        const float* Bf = reinterpret_cast<const float*>(B);
        #pragma unroll
        for (int i = 0; i < 4; i++)
            #pragma unroll
            for (int kk = 0; kk < 4; kk++) {
                float av = Af[i * 4 + kk];
                #pragma unroll
                for (int j = 0; j < 4; j++)
                    acc[i][j] = fmaf(av, Bf[kk * 4 + j], acc[i][j]);
            }
    }
    #pragma unroll
    for (int i = 0; i < 4; i++) {
        int m = row0 + r4 + i;
        if (m >= N) continue;
        ushort4 o;
        o.x = f2bf(acc[i][0]); o.y = f2bf(acc[i][1]);
        o.z = f2bf(acc[i][2]); o.w = f2bf(acc[i][3]);
        *reinterpret_cast<ushort4*>(&OUT[(size_t)m * OSTR + c4]) = o;
    }
}

// 8 bf16 (uint4) * w accumulated into acc[8]
__device__ __forceinline__ void fma_bf8(uint4 q, float w, float* acc) {
    acc[0] = fmaf(__uint_as_float(q.x << 16),          w, acc[0]);
    acc[1] = fmaf(__uint_as_float(q.x & 0xffff0000u),  w, acc[1]);
    acc[2] = fmaf(__uint_as_float(q.y << 16),          w, acc[2]);
    acc[3] = fmaf(__uint_as_float(q.y & 0xffff0000u),  w, acc[3]);
    acc[4] = fmaf(__uint_as_float(q.z << 16),          w, acc[4]);
    acc[5] = fmaf(__uint_as_float(q.z & 0xffff0000u),  w, acc[5]);
    acc[6] = fmaf(__uint_as_float(q.w << 16),          w, acc[6]);
    acc[7] = fmaf(__uint_as_float(q.w & 0xffff0000u),  w, acc[7]);
}

// ---------------- layer-1 aggregation: h = relu(agg + xw/deg + b1), F=64 ----------------
// One wave per node. Lane i: edge-subslot r=i>>3, feature-block b=i&7.
// One uint4 load/lane => 8 rows per wave vmem instruction.

__global__ __launch_bounds__(256) void agg1_relu(const u16* __restrict__ xw,
                                                 const int* __restrict__ csr_src,
                                                 const int* __restrict__ cnt,
                                                 const float* __restrict__ dinv,
                                                 const float* __restrict__ bias,
                                                 float* __restrict__ h, int N) {
    int v = (blockIdx.x * 256 + threadIdx.x) >> 6;
    int lane = threadIdx.x & 63;
    if (v >= N) return;
    int raw = csr_src[v * CAP + lane];            // speculative (in-buffer, masked below)
    int c = cnt[v]; if (c > CAP - 1) c = CAP - 1; // reserve a slot for the self-edge
    float dv = dinv[v];
    int sl; float wl;
    if (lane < c)       { sl = raw; wl = dinv[sl] * dv; }
    else if (lane == c) { sl = v;   wl = dv * dv; }
    else                { sl = 0;   wl = 0.f; }
    const int ce = c + 1;
    const int r = lane >> 3, b = lane & 7;
    float acc[8] = {};
    for (int j = 0; j < ce; j += 8) {
        int   se = __shfl(sl, j + r);
        float we = __shfl(wl, j + r);
        uint4 q = *reinterpret_cast<const uint4*>(&xw[(size_t)se * 64 + b * 8]);
        fma_bf8(q, we, acc);
    }
    #pragma unroll
    for (int u = 0; u < 8; u++) {
        acc[u] += __shfl_xor(acc[u], 8);
        acc[u] += __shfl_xor(acc[u], 16);
        acc[u] += __shfl_xor(acc[u], 32);
    }
    if (r == 0) {
        float o[8];
        #pragma unroll
        for (int u = 0; u < 8; u++)
            o[u] = fmaxf(acc[u] + bias[b * 8 + u], 0.f);
        float* dstp = &h[(size_t)v * 64 + b * 8];
        *reinterpret_cast<float4*>(dstp)     = make_float4(o[0], o[1], o[2], o[3]);
        *reinterpret_cast<float4*>(dstp + 4) = make_float4(o[4], o[5], o[6], o[7]);
    }
}

// ---------------- layer-2 aggregation fused with log_softmax, F=47 (rows padded to 64) ----------

__global__ __launch_bounds__(256) void agg2_lsm(const u16* __restrict__ hw,
                                                const int* __restrict__ csr_src,
                                                const int* __restrict__ cnt,
                                                const float* __restrict__ dinv,
                                                const float* __restrict__ bias,
                                                float* __restrict__ out, int N) {
    int v = (blockIdx.x * 256 + threadIdx.x) >> 6;
    int lane = threadIdx.x & 63;
    if (v >= N) return;
    int raw = csr_src[v * CAP + lane];
    int c = cnt[v]; if (c > CAP - 1) c = CAP - 1;
    float dv = dinv[v];
    int sl; float wl;
    if (lane < c)       { sl = raw; wl = dinv[sl] * dv; }
    else if (lane == c) { sl = v;   wl = dv * dv; }
    else                { sl = 0;   wl = 0.f; }
    const int ce = c + 1;
    const int r = lane >> 3, b = lane & 7;
    float acc[8] = {};
    for (int j = 0; j < ce; j += 8) {
        int   se = __shfl(sl, j + r);
        float we = __shfl(wl, j + r);
        uint4 q = *reinterpret_cast<const uint4*>(&hw[(size_t)se * 64 + b * 8]);
        fma_bf8(q, we, acc);
    }
    #pragma unroll
    for (int u = 0; u < 8; u++) {
        acc[u] += __shfl_xor(acc[u], 8);
        acc[u] += __shfl_xor(acc[u], 16);
        acc[u] += __shfl_xor(acc[u], 32);
    }
    // every lane now holds the full sums for its feature block b (features b*8+u)
    const int f0 = b * 8;
    float val[8];
    #pragma unroll
    for (int u = 0; u < 8; u++) {
        int f = f0 + u;
        val[u] = (f < 47) ? acc[u] + bias[f] : -INFINITY;
    }
    float m = val[0];
    #pragma unroll
    for (int u = 1; u < 8; u++) m = fmaxf(m, val[u]);
    m = fmaxf(m, __shfl_xor(m, 1));
    m = fmaxf(m, __shfl_xor(m, 2));
    m = fmaxf(m, __shfl_xor(m, 4));
    float s = 0.f;
    #pragma unroll
    for (int u = 0; u < 8; u++)
        s += (f0 + u < 47) ? __expf(val[u] - m) : 0.f;
    s += __shfl_xor(s, 1);
    s += __shfl_xor(s, 2);
    s += __shfl_xor(s, 4);
    float ls = m + __logf(s);
    if (r == 0) {
        #pragma unroll
        for (int u = 0; u < 8; u++) {
            int f = f0 + u;
            if (f < 47) out[(size_t)v * 47 + f] = val[u] - ls;
        }
    }
}

// ---------------- launch ----------------

extern "C" void kernel_launch(void* const* d_in, const int* in_sizes, int n_in,
                              void* d_out, int out_size, void* d_ws, size_t ws_size,
                              hipStream_t stream) {
    const float* x  = (const float*)d_in[0];
    const int*   ei = (const int*)d_in[1];
    const float* W1 = (const float*)d_in[2];
    const float* b1 = (const float*)d_in[3];
    const float* W2 = (const float*)d_in[4];
    const float* b2 = (const float*)d_in[5];
    float* out = (float*)d_out;

    const int N = in_sizes[0] / 128;
    const int E = in_sizes[1] / 2;
    const int* src = ei;
    const int* dst = ei + E;

    char* ws = (char*)d_ws;
    size_t off = 0;
    auto alloc = [&](size_t bytes) {
        void* p = ws + off;
        off += (bytes + 255) & ~(size_t)255;
        return p;
    };
    int*   cnt     = (int*)  alloc((size_t)N * 4);
    float* dinv    = (float*)alloc((size_t)N * 4);
    int*   csr_src = (int*)  alloc((size_t)N * CAP * 4);
    u16*   xw1     = (u16*)  alloc((size_t)N * 64 * 2);   // bf16 [N,64], 128B rows
    float* hbuf    = (float*)alloc((size_t)N * 64 * 4);   // fp32 [N,64]
    u16*   hw2     = (u16*)  alloc((size_t)N * 64 * 2);   // bf16 [N,64], 47 used + zeros

    const int chunk = (N + 7) / 8;

    hipMemsetAsync(cnt, 0, (size_t)N * 4, stream);
    build_csr<<<1024, 256, 0, stream>>>(src, dst, cnt, csr_src, E, chunk);
    compute_dinv<<<(N + 255) / 256, 256, 0, stream>>>(cnt, dinv, N);

    gemm_tiled<128, 64, 64><<<(N + 63) / 64, 256, 0, stream>>>(x, W1, xw1, N);
    agg1_relu<<<(N + 3) / 4, 256, 0, stream>>>(xw1, csr_src, cnt, dinv, b1, hbuf, N);
    gemm_tiled<64, 47, 64><<<(N + 63) / 64, 256, 0, stream>>>(hbuf, W2, hw2, N);
    agg2_lsm<<<(N + 3) / 4, 256, 0, stream>>>(hw2, csr_src, cnt, dinv, b2, out, N);
}